// Round 1
// baseline (185.450 us; speedup 1.0000x reference)
//
#include <hip/hip_runtime.h>

// Problem constants (fixed by the reference):
//   preds: (B=64, N=2048, F=4) fp32, targs: (B=64, M=2048, F=4) fp32,
//   subcoef: (D=2,) fp32. Distance uses only features [0:2).
constexpr int B = 64;
constexpr int N = 2048;
constexpr int M = 2048;
constexpr int F = 4;
constexpr int BLOCK = 256;

// One direction of the bidirectional NN loss:
//   for each src point (per batch), find nearest dst point (squared L2 over 2D),
//   accumulate |src - dst_nn| . coef  into *out (device-scope atomic).
// use_coef=1 applies subcoef (preds->targs direction), 0 uses (1,1).
__global__ void __launch_bounds__(BLOCK)
nnloss_dir_kernel(const float* __restrict__ src,   // (B, NS, F)
                  const float* __restrict__ dst,   // (B, ND, F)
                  const float* __restrict__ subcoef,
                  int use_coef,
                  float* __restrict__ out) {
    __shared__ float2 sdst[M];           // 16 KB: all dst points of this batch
    __shared__ float  wsum[BLOCK / 64];  // per-wave partials

    const int b   = blockIdx.y;
    const int tid = threadIdx.x;

    // Stage this batch's dst points (x,y) into LDS. (b*M + i)*F is 16B-aligned,
    // so a float2 load of elements {0,1} is aligned.
    const float* dstb = dst + (size_t)b * M * F;
    for (int i = tid; i < M; i += BLOCK) {
        sdst[i] = *reinterpret_cast<const float2*>(dstb + (size_t)i * F);
    }
    __syncthreads();

    // Each thread owns one src point.
    const int n = blockIdx.x * BLOCK + tid;
    const float2 p = *reinterpret_cast<const float2*>(src + ((size_t)b * N + n) * F);

    float best = 3.4028235e38f;
    int   bidx = 0;
    #pragma unroll 8
    for (int m = 0; m < M; ++m) {
        const float2 t = sdst[m];        // broadcast read: conflict-free
        const float dx = p.x - t.x;
        const float dy = p.y - t.y;
        const float d2 = dx * dx + dy * dy;
        // strict < keeps the FIRST minimal index (matches jnp.argmin).
        if (d2 < best) { best = d2; bidx = m; }
    }

    const float2 q = sdst[bidx];
    float c0 = 1.0f, c1 = 1.0f;
    if (use_coef) { c0 = subcoef[0]; c1 = subcoef[1]; }
    float contrib = fabsf(p.x - q.x) * c0 + fabsf(p.y - q.y) * c1;

    // Wave (64-lane) shuffle reduction, then block reduction, then one atomic.
    #pragma unroll
    for (int off = 32; off > 0; off >>= 1) {
        contrib += __shfl_down(contrib, off, 64);
    }
    const int wave = tid >> 6;
    if ((tid & 63) == 0) wsum[wave] = contrib;
    __syncthreads();
    if (tid == 0) {
        float s = 0.0f;
        #pragma unroll
        for (int w = 0; w < BLOCK / 64; ++w) s += wsum[w];
        atomicAdd(out, s);
    }
}

extern "C" void kernel_launch(void* const* d_in, const int* in_sizes, int n_in,
                              void* d_out, int out_size, void* d_ws, size_t ws_size,
                              hipStream_t stream) {
    const float* preds   = (const float*)d_in[0];
    const float* targs   = (const float*)d_in[1];
    const float* subcoef = (const float*)d_in[2];
    float* out = (float*)d_out;

    // d_out is poisoned (0xAA) before every launch; zero it stream-ordered.
    hipMemsetAsync(out, 0, sizeof(float), stream);

    dim3 grid(N / BLOCK, B);
    // Direction 1: preds -> nearest targ, weighted by subcoef.
    nnloss_dir_kernel<<<grid, BLOCK, 0, stream>>>(preds, targs, subcoef, 1, out);
    // Direction 2: targs -> nearest pred, unweighted.
    nnloss_dir_kernel<<<grid, BLOCK, 0, stream>>>(targs, preds, subcoef, 0, out);
}